// Round 9
// baseline (1729.438 us; speedup 1.0000x reference)
//
#include <hip/hip_runtime.h>
#include <math.h>

// MetaNETS Langevin sampler, MI355X — round 9.
// R8 lesson: split-K was right, per-thread-row transposes were wrong (lane-
// uncoalesced -> VMEM stall, VALUBusy 49->37). R9 = R6 base +
//  (1) full-width (256t) split-K GEMV phases using original coalesced
//      [j*HD+h] layouts; partials combined inline at consumers (6 barriers).
//  (2) tau scatter via ds_write_b16 per lane (2-way dword alias = free)
//      instead of pair-shfl+predicated b32 — kills 32 dependent shfls/epilogue.
//  (3) step-invariant shfl broadcasts hoisted out of the loop; gz uses
//      lane-coalesced prep-transposed Wd1zT.

#define B_TOT 2048
#define NPT   64
#define ZD    64
#define HD    128

typedef short bh8 __attribute__((ext_vector_type(8)));   // 8 x bf16 (4 VGPR)
typedef float fx4 __attribute__((ext_vector_type(4)));   // MFMA C/D

__device__ __forceinline__ float sigf(float x) {
  return __builtin_amdgcn_rcpf(1.0f + __expf(-x));
}
__device__ __forceinline__ unsigned int bfb(float x) {   // fp32 -> bf16 bits (RNE)
  unsigned int u = __float_as_uint(x);
  u += 0x7FFFu + ((u >> 16) & 1u);
  return u >> 16;
}
__device__ __forceinline__ unsigned int packbf(float a, float b) {
  unsigned int ua = __float_as_uint(a), ub = __float_as_uint(b);
  ua += 0x7FFFu + ((ua >> 16) & 1u);
  ub += 0x7FFFu + ((ub >> 16) & 1u);
  return (ua >> 16) | (ub & 0xFFFF0000u);
}
__device__ __forceinline__ float wsum64(float v) {
  #pragma unroll
  for (int d = 1; d < 64; d <<= 1) v += __shfl_xor(v, d, 64);
  return v;
}
__device__ __forceinline__ void wave_sync() {   // intra-wave LDS order + drain
  __builtin_amdgcn_wave_barrier();
  __builtin_amdgcn_s_waitcnt(0xC07F);           // lgkmcnt(0)
  __builtin_amdgcn_wave_barrier();
}

// B-frag arrays (bf16): frag[((kc*8+nt)*64+L)*8+j] = W[kc*32+(L>>4)*8+j][nt*16+(L&15)]
// arr0: Wd2  arr1: Wd2^T  arr2: We2  arr3: We3 ; then Wd1zT (fp32, [k*64+j]).
__global__ __launch_bounds__(256)
void prep_kernel(const float* __restrict__ Wd2, const float* __restrict__ We2,
                 const float* __restrict__ We3, const float* __restrict__ Wd1,
                 ushort* __restrict__ ws) {
  const int id = blockIdx.x * 256 + threadIdx.x;   // 65536 frag + 8192 Wd1zT
  if (id < 65536) {
    const int arr = id >> 14;
    const int e = id & 16383;
    const int j = e & 7, L = (e >> 3) & 63, nt = (e >> 9) & 7, kc = e >> 12;
    const int kk = kc * 32 + (L >> 4) * 8 + j, nn = nt * 16 + (L & 15);
    float v;
    if      (arr == 0) v = Wd2[kk * HD + nn];
    else if (arr == 1) v = Wd2[nn * HD + kk];    // Wd2^T
    else if (arr == 2) v = We2[kk * HD + nn];
    else               v = We3[kk * HD + nn];
    ws[id] = (ushort)bfb(v);
  } else if (id < 65536 + 8192) {
    const int e = id - 65536;                    // Wd1zT[k*64+j] = Wd1[j*128+k]
    ((float*)(ws + 65536))[e] = Wd1[(e & 63) * HD + (e >> 6)];
  }
}

__global__ __launch_bounds__(256, 1)
void metanets_kernel(
    const float* __restrict__ x_ctx, const float* __restrict__ y_ctx,
    const float* __restrict__ mask,  const float* __restrict__ z0,
    const float* __restrict__ noises,
    const float* __restrict__ We1, const float* __restrict__ be1,
    const float* __restrict__ be2, const float* __restrict__ be3,
    const float* __restrict__ Wd1, const float* __restrict__ bd1,
    const float* __restrict__ bd2, const float* __restrict__ Wd3,
    const float* __restrict__ bd3,
    const float* __restrict__ Wf1, const float* __restrict__ bf1,
    const float* __restrict__ Wf2, const float* __restrict__ bf2,
    const float* __restrict__ Wf3, const float* __restrict__ bf3,
    const ushort* __restrict__ wsfrag,
    float* __restrict__ out, int steps, float dt, float dco)
{
  __shared__ __align__(16) unsigned int h1f[4096];  // h1 / tau (aliased) A-frags
  __shared__ float vin[200];      // z[0:64) r[64:192) t at [192]
  __shared__ float zwP[256];      // zW1 split-K partials
  __shared__ float scratchP[512]; // f1P (P1) -> dsumP (P3/4) -> f3P|gzP (P6)
  __shared__ float f2P[256];      // f2 split-K partials
  __shared__ float dsumC[128];
  __shared__ float f1sh[128];
  __shared__ float f2sh[128];
  __shared__ float bd2sh[128], wd3sh[128], wx0sh[128], wx1sh[128];

  unsigned int* const tauf = h1f;
  ushort* const tauh = (ushort*)h1f;

  const int tid = threadIdx.x;
  const int lane = tid & 63;                                  // context point
  const int w = __builtin_amdgcn_readfirstlane(tid >> 6);     // wave = m-tile
  const int b = blockIdx.x;
  const int rr = lane & 15, qq = lane >> 4;
  const int hcol = tid & 127, khalf = tid >> 7;               // split-K ids

  const bh8* Wd2f  = (const bh8*)(wsfrag);
  const bh8* Wd2Tf = (const bh8*)(wsfrag + 16384);
  const bh8* We2f  = (const bh8*)(wsfrag + 32768);
  const bh8* We3f  = (const bh8*)(wsfrag + 49152);
  const float* Wd1zT = (const float*)(wsfrag + 65536);

  const float x0v = x_ctx[(b*NPT + lane)*2 + 0];
  const float x1v = x_ctx[(b*NPT + lane)*2 + 1];
  const float yv  = y_ctx[b*NPT + lane];
  const float mkv = mask[b*NPT + lane];
  const float inv_msum = 1.0f / fmaxf(wsum64(mkv), 1e-6f);
  const float bd3v = bd3[0];

  // step-invariant per-C-row broadcasts (points w*16 + 4*qq + g)
  float x0q[4], x1q[4], yq[4], mkq[4];
  #pragma unroll
  for (int g = 0; g < 4; ++g) {
    const int src = w*16 + qq*4 + g;
    x0q[g] = __shfl(x0v, src, 64);
    x1q[g] = __shfl(x1v, src, 64);
    yq[g]  = __shfl(yv,  src, 64);
    mkq[g] = __shfl(mkv, src, 64);
  }

  if (tid < 64) vin[tid] = z0[b*ZD + tid];
  if (tid == 192) vin[192] = 0.0f;     // t for step 0
  if (tid < 128) {
    bd2sh[tid] = bd2[tid];
    wd3sh[tid] = Wd3[tid];
    wx0sh[tid] = Wd1[64*HD + tid];
    wx1sh[tid] = Wd1[65*HD + tid];
  }
  __syncthreads();

  // ================= encoder =================
  #pragma unroll
  for (int quad = 0; quad < 4; ++quad) {       // enc L1 -> h1f (kc=w slice)
    unsigned int pw[4];
    #pragma unroll
    for (int jj = 0; jj < 8; jj += 2) {
      const int k = 32*w + 8*quad + jj;
      const float sA = be1[k]   + x0v*We1[k]   + x1v*We1[HD+k]   + yv*We1[2*HD+k];
      const float sB = be1[k+1] + x0v*We1[k+1] + x1v*We1[HD+k+1] + yv*We1[2*HD+k+1];
      pw[jj>>1] = packbf(sA*sigf(sA), sB*sigf(sB));
    }
    uint4 v4; v4.x = pw[0]; v4.y = pw[1]; v4.z = pw[2]; v4.w = pw[3];
    ((uint4*)h1f)[(w*4 + qq)*64 + quad*16 + rr] = v4;
  }
  __syncthreads();

  {  // enc L2 (MFMA) -> tauf (aliased, b16 scatter)
    bh8 af[4];
    #pragma unroll
    for (int kc = 0; kc < 4; ++kc)
      af[kc] = ((const bh8*)h1f)[(kc*4 + w)*64 + lane];
    wave_sync();
    #pragma unroll 1
    for (int half = 0; half < 2; ++half) {
      const int h4 = half*4;
      fx4 acc[4];
      #pragma unroll
      for (int i = 0; i < 4; ++i) {
        const float bv = be2[(h4+i)*16 + rr];
        acc[i] = (fx4){bv, bv, bv, bv};
      }
      #pragma unroll
      for (int i = 0; i < 4; ++i) {
        const int nt = h4 + i;
        acc[i] = __builtin_amdgcn_mfma_f32_16x16x32_bf16(af[0], We2f[(0*8+nt)*64+lane], acc[i], 0,0,0);
        acc[i] = __builtin_amdgcn_mfma_f32_16x16x32_bf16(af[1], We2f[(1*8+nt)*64+lane], acc[i], 0,0,0);
        acc[i] = __builtin_amdgcn_mfma_f32_16x16x32_bf16(af[2], We2f[(2*8+nt)*64+lane], acc[i], 0,0,0);
        acc[i] = __builtin_amdgcn_mfma_f32_16x16x32_bf16(af[3], We2f[(3*8+nt)*64+lane], acc[i], 0,0,0);
      }
      #pragma unroll
      for (int i = 0; i < 4; ++i) {
        const int nt = h4 + i;
        const int ubase = (((nt>>1)*4 + w)*64 + (2*(nt&1) + (rr>>3))*16 + 4*qq)*8 + (rr&7);
        #pragma unroll
        for (int g = 0; g < 4; ++g) {
          const float s2 = acc[i][g];
          tauh[ubase + g*8] = (ushort)bfb(s2 * sigf(s2));
        }
      }
    }
  }
  wave_sync();

  {  // enc L3 (MFMA) + masked mean-pool -> vin[64..192)
    bh8 tf[4];
    #pragma unroll
    for (int kc = 0; kc < 4; ++kc)
      tf[kc] = ((const bh8*)tauf)[(kc*4 + w)*64 + lane];
    #pragma unroll 1
    for (int half = 0; half < 2; ++half) {
      const int h4 = half*4;
      fx4 acc[4];
      #pragma unroll
      for (int i = 0; i < 4; ++i) {
        const float bv = be3[(h4+i)*16 + rr];
        acc[i] = (fx4){bv, bv, bv, bv};
      }
      #pragma unroll
      for (int i = 0; i < 4; ++i) {
        const int nt = h4 + i;
        acc[i] = __builtin_amdgcn_mfma_f32_16x16x32_bf16(tf[0], We3f[(0*8+nt)*64+lane], acc[i], 0,0,0);
        acc[i] = __builtin_amdgcn_mfma_f32_16x16x32_bf16(tf[1], We3f[(1*8+nt)*64+lane], acc[i], 0,0,0);
        acc[i] = __builtin_amdgcn_mfma_f32_16x16x32_bf16(tf[2], We3f[(2*8+nt)*64+lane], acc[i], 0,0,0);
        acc[i] = __builtin_amdgcn_mfma_f32_16x16x32_bf16(tf[3], We3f[(3*8+nt)*64+lane], acc[i], 0,0,0);
      }
      #pragma unroll
      for (int i = 0; i < 4; ++i) {
        float pv = mkq[0]*acc[i][0] + mkq[1]*acc[i][1]
                 + mkq[2]*acc[i][2] + mkq[3]*acc[i][3];
        pv += __shfl_xor(pv, 16, 64);
        pv += __shfl_xor(pv, 32, 64);
        if (lane < 16) scratchP[w*128 + (h4+i)*16 + lane] = pv;
      }
    }
  }
  __syncthreads();
  if (tid < 128)
    vin[64 + tid] = (scratchP[tid] + scratchP[128+tid]
                   + scratchP[256+tid] + scratchP[384+tid]) * inv_msum;
  __syncthreads();

  // ================= Langevin step loop =================
  for (int st = 0; st < steps; ++st) {
    const float t = (float)st * dt;

    // P1 (256-wide): f1 partials over vin[0..193) + zW1 partials (coalesced W)
    {
      float p0 = khalf ? 0.0f : bf1[hcol];
      const int jb = khalf ? 96 : 0, je = khalf ? 193 : 96;
      #pragma unroll 4
      for (int j = jb; j < je; ++j)
        p0 = fmaf(vin[j], Wf1[j*HD + hcol], p0);
      scratchP[tid] = p0;

      float a0 = khalf ? 0.0f : bd1[hcol];
      const int zb = khalf * 32;
      #pragma unroll 4
      for (int j = zb; j < zb + 32; ++j)
        a0 = fmaf(vin[j], Wd1[j*HD + hcol], a0);
      zwP[tid] = a0;
    }
    __syncthreads();   // s1

    // P2: dec L1 -> h1f (kc=w slice, inline zwP combine) + f1 combine
    #pragma unroll
    for (int quad = 0; quad < 4; ++quad) {
      unsigned int pw[4];
      #pragma unroll
      for (int jj = 0; jj < 8; jj += 2) {
        const int k = 32*w + 8*quad + jj;
        const float sA = zwP[k]   + zwP[k+128]   + x0v*wx0sh[k]   + x1v*wx1sh[k];
        const float sB = zwP[k+1] + zwP[k+1+128] + x0v*wx0sh[k+1] + x1v*wx1sh[k+1];
        pw[jj>>1] = packbf(sA*sigf(sA), sB*sigf(sB));
      }
      uint4 v4; v4.x = pw[0]; v4.y = pw[1]; v4.z = pw[2]; v4.w = pw[3];
      ((uint4*)h1f)[(w*4 + qq)*64 + quad*16 + rr] = v4;
    }
    if (tid < 128) {
      const float a = scratchP[tid] + scratchP[tid + 128];
      f1sh[tid] = a * sigf(a);
    }
    __syncthreads();   // s2

    // P3+P4: fused fwd+bwd per wave's m-tile (wave-local; tau aliases h1f)
    {
      bh8 af[4];
      #pragma unroll
      for (int kc = 0; kc < 4; ++kc)
        af[kc] = ((const bh8*)h1f)[(kc*4 + w)*64 + lane];
      wave_sync();   // af in regs before aliased b16 scatter
      float da[4] = {0.f, 0.f, 0.f, 0.f};
      #pragma unroll 1
      for (int half = 0; half < 2; ++half) {
        const int h4 = half*4;
        fx4 acc[4];
        #pragma unroll
        for (int i = 0; i < 4; ++i) {
          const float bv = bd2sh[(h4+i)*16 + rr];
          acc[i] = (fx4){bv, bv, bv, bv};
        }
        #pragma unroll
        for (int i = 0; i < 4; ++i) {
          const int nt = h4 + i;
          acc[i] = __builtin_amdgcn_mfma_f32_16x16x32_bf16(af[0], Wd2f[(0*8+nt)*64+lane], acc[i], 0,0,0);
          acc[i] = __builtin_amdgcn_mfma_f32_16x16x32_bf16(af[1], Wd2f[(1*8+nt)*64+lane], acc[i], 0,0,0);
          acc[i] = __builtin_amdgcn_mfma_f32_16x16x32_bf16(af[2], Wd2f[(2*8+nt)*64+lane], acc[i], 0,0,0);
          acc[i] = __builtin_amdgcn_mfma_f32_16x16x32_bf16(af[3], Wd2f[(3*8+nt)*64+lane], acc[i], 0,0,0);
        }
        #pragma unroll
        for (int i = 0; i < 4; ++i) {
          const int nt = h4 + i;
          const float w3 = wd3sh[nt*16 + rr];
          const int ubase = (((nt>>1)*4 + w)*64 + (2*(nt&1) + (rr>>3))*16 + 4*qq)*8 + (rr&7);
          #pragma unroll
          for (int g = 0; g < 4; ++g) {
            const float s2 = acc[i][g];
            const float sg = sigf(s2);
            da[g] = fmaf(s2*sg, w3, da[g]);
            tauh[ubase + g*8] = (ushort)bfb(w3 * (sg * fmaf(s2, 1.0f - sg, 1.0f)));
          }
        }
      }
      float ebw[4];
      #pragma unroll
      for (int g = 0; g < 4; ++g) {
        float v = da[g];
        v += __shfl_xor(v, 1, 64);
        v += __shfl_xor(v, 2, 64);
        v += __shfl_xor(v, 4, 64);
        v += __shfl_xor(v, 8, 64);
        ebw[g] = t * mkq[g] * (v + bd3v - yq[g]);
      }
      wave_sync();   // tau scatter visible (wave-local)
      bh8 tf[4];
      #pragma unroll
      for (int kc = 0; kc < 4; ++kc)
        tf[kc] = ((const bh8*)tauf)[(kc*4 + w)*64 + lane];
      #pragma unroll 1
      for (int half = 0; half < 2; ++half) {
        const int h4 = half*4;
        fx4 u[4];
        #pragma unroll
        for (int i = 0; i < 4; ++i) u[i] = (fx4){0.f, 0.f, 0.f, 0.f};
        #pragma unroll
        for (int i = 0; i < 4; ++i) {
          const int nt = h4 + i;
          u[i] = __builtin_amdgcn_mfma_f32_16x16x32_bf16(tf[0], Wd2Tf[(0*8+nt)*64+lane], u[i], 0,0,0);
          u[i] = __builtin_amdgcn_mfma_f32_16x16x32_bf16(tf[1], Wd2Tf[(1*8+nt)*64+lane], u[i], 0,0,0);
          u[i] = __builtin_amdgcn_mfma_f32_16x16x32_bf16(tf[2], Wd2Tf[(2*8+nt)*64+lane], u[i], 0,0,0);
          u[i] = __builtin_amdgcn_mfma_f32_16x16x32_bf16(tf[3], Wd2Tf[(3*8+nt)*64+lane], u[i], 0,0,0);
        }
        #pragma unroll
        for (int i = 0; i < 4; ++i) {
          const int nt = h4 + i;
          const int k = nt*16 + rr;
          const float zv = zwP[k] + zwP[k+128];
          const float wa = wx0sh[k];
          const float wb = wx1sh[k];
          float snt = 0.f;
          #pragma unroll
          for (int g = 0; g < 4; ++g) {
            const float s1 = zv + x0q[g]*wa + x1q[g]*wb;
            const float sg = sigf(s1);
            snt += ebw[g] * (sg * fmaf(s1, 1.0f - sg, 1.0f)) * u[i][g];
          }
          snt += __shfl_xor(snt, 16, 64);
          snt += __shfl_xor(snt, 32, 64);
          if (lane < 16) scratchP[w*128 + nt*16 + lane] = snt;   // dsumP
        }
      }
    }
    // f2 partials (256-wide, independent of bwd results; f1sh ready since s2)
    {
      float p0 = khalf ? 0.0f : bf2[hcol];
      const int jb = khalf * 64;
      #pragma unroll 4
      for (int j = jb; j < jb + 64; ++j)
        p0 = fmaf(f1sh[j], Wf2[j*HD + hcol], p0);
      f2P[tid] = p0;
    }
    __syncthreads();   // s3

    // P5: dsum combine + f2 combine (tid<128)
    if (tid < 128) {
      dsumC[tid] = scratchP[tid] + scratchP[128+tid]
                 + scratchP[256+tid] + scratchP[384+tid];
      const float a = f2P[tid] + f2P[tid + 128];
      f2sh[tid] = a * sigf(a);
    }
    __syncthreads();   // s4

    // P6 (256-wide): f3 partials (tid<128) | gz partials (tid>=128)
    if (tid < 128) {
      const int j = tid & 63, hh = tid >> 6;
      float p0 = hh ? 0.0f : bf3[j];
      const int hb = hh * 64;
      #pragma unroll 4
      for (int h = hb; h < hb + 64; ++h)
        p0 = fmaf(f2sh[h], Wf3[h*ZD + j], p0);
      scratchP[tid] = p0;                        // f3P
    } else {
      const int e = tid - 128;
      const int j = e & 63, hh = e >> 6;
      float p0 = 0.f;
      const int hb = hh * 64;
      #pragma unroll 4
      for (int h = hb; h < hb + 64; ++h)
        p0 = fmaf(dsumC[h], Wd1zT[h*ZD + j], p0);
      scratchP[tid] = p0;                        // gzP at [128..256)
    }
    __syncthreads();   // s5

    // P7: z update (+ next-step t)
    if (tid < 64) {
      const float bj  = scratchP[tid] + scratchP[tid + 64];
      const float gzv = scratchP[128 + tid] + scratchP[192 + tid];
      const float zold = vin[tid];
      float g = zold + gzv;                      // t folded into ebw
      g = fminf(fmaxf(g, -100.0f), 100.0f);
      vin[tid] = zold + (bj - g) * dt
               + dco * noises[(size_t)st * (B_TOT * ZD) + b * ZD + tid];
    }
    if (tid == 64) vin[192] = (float)(st + 1) * dt;
    __syncthreads();   // s6
  }

  if (tid < 64) out[b * ZD + tid] = vin[tid];
}

extern "C" void kernel_launch(void* const* d_in, const int* in_sizes, int n_in,
                              void* d_out, int out_size, void* d_ws, size_t ws_size,
                              hipStream_t stream) {
  const float* x_ctx  = (const float*)d_in[0];
  const float* y_ctx  = (const float*)d_in[1];
  const float* mask   = (const float*)d_in[2];
  const float* z0     = (const float*)d_in[3];
  const float* noises = (const float*)d_in[4];
  const float* We1 = (const float*)d_in[5];  const float* be1 = (const float*)d_in[6];
  const float* We2 = (const float*)d_in[7];  const float* be2 = (const float*)d_in[8];
  const float* We3 = (const float*)d_in[9];  const float* be3 = (const float*)d_in[10];
  const float* Wd1 = (const float*)d_in[11]; const float* bd1 = (const float*)d_in[12];
  const float* Wd2 = (const float*)d_in[13]; const float* bd2 = (const float*)d_in[14];
  const float* Wd3 = (const float*)d_in[15]; const float* bd3 = (const float*)d_in[16];
  const float* Wf1 = (const float*)d_in[17]; const float* bf1 = (const float*)d_in[18];
  const float* Wf2 = (const float*)d_in[19]; const float* bf2 = (const float*)d_in[20];
  const float* Wf3 = (const float*)d_in[21]; const float* bf3 = (const float*)d_in[22];

  const int steps = in_sizes[4] / (B_TOT * ZD);
  const float dt  = 1.0f / (float)steps;
  const float dco = (float)sqrt(2.0 / (double)steps);

  ushort* wsu = (ushort*)d_ws;   // 128KB frags + 32KB Wd1zT

  hipLaunchKernelGGL(prep_kernel, dim3(288), dim3(256), 0, stream,
                     Wd2, We2, We3, Wd1, wsu);
  hipLaunchKernelGGL(metanets_kernel, dim3(B_TOT), dim3(256), 0, stream,
      x_ctx, y_ctx, mask, z0, noises,
      We1, be1, be2, be3,
      Wd1, bd1, bd2, Wd3, bd3,
      Wf1, bf1, Wf2, bf2, Wf3, bf3,
      wsu, (float*)d_out, steps, dt, dco);
}